// Round 3
// baseline (252.590 us; speedup 1.0000x reference)
//
#include <hip/hip_runtime.h>
#include <math.h>

// Problem constants (N = 1024)
#define M_ROWS  81920            // 1024*8*10 score rows
#define NCOLS   4096
#define KPAD    64               // 45 padded to 64 (2 MFMA k-tiles)
#define NCHUNK  8
#define CHUNKC  (NCOLS / NCHUNK) // 512 cols per chunk
#define CTILES  (CHUNKC / 16)    // 32 col-tiles per chunk
#define LO_SCALE 4096.0f         // 2^12: keeps f16 residuals out of subnormal range
#define INV_LO   (1.0f / 4096.0f)

typedef _Float16 f16x8 __attribute__((ext_vector_type(8)));
typedef float    f32x4 __attribute__((ext_vector_type(4)));

// ws layout (~16.8 MB):
//   A    : _Float16[81920 * 64]                         10.49 MB
//   Bhi  : _Float16[4096 * 64]   ([col][k], pad zeroed)  0.52 MB
//   Blo  : _Float16[4096 * 64]   (residual * 2^12)       0.52 MB
//   pbest: float[81920 * 8]                              2.62 MB
//   pidx : int  [81920 * 8]                              2.62 MB

// ---------------------------------------------------------------------------
// Build A: y[row][k] = sign(x4·S - T - 1e-4), exactly ±1/0 in f16. Pad k>=45.
__global__ void build_A_kernel(const float* __restrict__ x,
                               const float* __restrict__ S,
                               const float* __restrict__ T,
                               _Float16* __restrict__ A) {
    const int row = blockIdx.x * blockDim.x + threadIdx.x;
    if (row >= M_ROWS) return;
    const int pair = row / 10;
    const int c2   = row - pair * 10;
    const int a    = pair >> 3;
    const int b    = pair & 7;
    const float* xp = x + a * 480 + b * 60;
    _Float16 y[KPAD];
    #pragma unroll
    for (int j = 0; j < 45; ++j) {
        const int c = c2 * 3 + j / 15;    // constant-folded by unroll
        const int k = j % 15;
        const float x0 = xp[c * 2 + 0];
        const float x1 = xp[c * 2 + 1];
        float v = x0 * S[(c * 2 + 0) * 15 + k] + x1 * S[(c * 2 + 1) * 15 + k];
        v = v - T[c * 15 + k] - 1e-4f;
        y[j] = (v > 0.f) ? (_Float16)1.f : ((v < 0.f) ? (_Float16)-1.f : (_Float16)0.f);
    }
    #pragma unroll
    for (int j = 45; j < KPAD; ++j) y[j] = (_Float16)0.f;
    f16x8* dst = (f16x8*)(A + (size_t)row * KPAD);   // 128 B/row, 16B-aligned
    const f16x8* src = (const f16x8*)y;
    #pragma unroll
    for (int q = 0; q < KPAD / 8; ++q) dst[q] = src[q];
}

// ---------------------------------------------------------------------------
// Build B: split H (45 x 4096, [d][n]) into hi/lo f16 in [n][k] layout so the
// MFMA B-fragment (B[k=quad*8+j][n=lane&15]) is 8 contiguous halves per lane.
__global__ void build_B_kernel(const float* __restrict__ H,
                               _Float16* __restrict__ Bhi,
                               _Float16* __restrict__ Blo) {
    const int n = blockIdx.x * blockDim.x + threadIdx.x;
    if (n >= NCOLS) return;
    _Float16 hi[KPAD], lo[KPAD];
    #pragma unroll
    for (int k = 0; k < 45; ++k) {
        const float h = H[k * NCOLS + n];
        const _Float16 h1 = (_Float16)h;
        hi[k] = h1;
        lo[k] = (_Float16)((h - (float)h1) * LO_SCALE);
    }
    #pragma unroll
    for (int k = 45; k < KPAD; ++k) { hi[k] = (_Float16)0.f; lo[k] = (_Float16)0.f; }
    f16x8* dh = (f16x8*)(Bhi + (size_t)n * KPAD);
    f16x8* dl = (f16x8*)(Blo + (size_t)n * KPAD);
    const f16x8* sh = (const f16x8*)hi;
    const f16x8* sl = (const f16x8*)lo;
    #pragma unroll
    for (int q = 0; q < KPAD / 8; ++q) { dh[q] = sh[q]; dl[q] = sl[q]; }
}

// ---------------------------------------------------------------------------
// MFMA GEMM + fused argmax, software-pipelined B prefetch.
// wave = 64 rows (4 row-tiles) x 512-col chunk; block's 4 waves share a chunk.
// C layout (m89-verified): row = quad*4 + reg, col = lane&15.
__global__ __launch_bounds__(256) void score_argmax_kernel(
        const _Float16* __restrict__ A,
        const _Float16* __restrict__ Bhi,
        const _Float16* __restrict__ Blo,
        float* __restrict__ pbest,
        int*   __restrict__ pidx) {
    const int tid  = threadIdx.x;
    const int lane = tid & 63;
    const int l15  = lane & 15;
    const int quad = lane >> 4;
    const int w     = blockIdx.x * 4 + (tid >> 6);    // [0, 10240)
    const int chunk = w / 1280;                        // block-uniform (1280 % 4 == 0)
    const int rg    = w - chunk * 1280;
    const int rowbase = rg * 64;

    // A fragments: A[m=lane&15][k=quad*8+j], 2 k-tiles x 4 row-tiles.
    f16x8 afr[4][2];
    #pragma unroll
    for (int rt = 0; rt < 4; ++rt)
        #pragma unroll
        for (int kt = 0; kt < 2; ++kt)
            afr[rt][kt] = *(const f16x8*)(A + (size_t)(rowbase + rt * 16 + l15) * KPAD
                                            + kt * 32 + quad * 8);

    float best[4][4];
    int   bidx[4][4];
    #pragma unroll
    for (int rt = 0; rt < 4; ++rt)
        #pragma unroll
        for (int r = 0; r < 4; ++r) { best[rt][r] = -INFINITY; bidx[rt][r] = 0; }

    const int colbase0 = chunk * CHUNKC;
    const _Float16* hbase = Bhi + (size_t)(colbase0 + l15) * KPAD + quad * 8;
    const _Float16* lbase = Blo + (size_t)(colbase0 + l15) * KPAD + quad * 8;
    const size_t ctstride = (size_t)16 * KPAD;   // halves per 16-col tile

    // prologue: load tile 0
    f16x8 bh0 = *(const f16x8*)(hbase);
    f16x8 bh1 = *(const f16x8*)(hbase + 32);
    f16x8 bl0 = *(const f16x8*)(lbase);
    f16x8 bl1 = *(const f16x8*)(lbase + 32);

    for (int ct = 0; ct < CTILES; ++ct) {
        // prefetch next tile (independent of this tile's MFMAs)
        f16x8 nh0, nh1, nl0, nl1;
        if (ct + 1 < CTILES) {
            const _Float16* hn = hbase + (size_t)(ct + 1) * ctstride;
            const _Float16* ln = lbase + (size_t)(ct + 1) * ctstride;
            nh0 = *(const f16x8*)(hn);
            nh1 = *(const f16x8*)(hn + 32);
            nl0 = *(const f16x8*)(ln);
            nl1 = *(const f16x8*)(ln + 32);
        }
        const int mycol = colbase0 + ct * 16 + l15;
        #pragma unroll
        for (int rt = 0; rt < 4; ++rt) {
            f32x4 ch = {0.f, 0.f, 0.f, 0.f};
            f32x4 cl = {0.f, 0.f, 0.f, 0.f};
            ch = __builtin_amdgcn_mfma_f32_16x16x32_f16(afr[rt][0], bh0, ch, 0, 0, 0);
            ch = __builtin_amdgcn_mfma_f32_16x16x32_f16(afr[rt][1], bh1, ch, 0, 0, 0);
            cl = __builtin_amdgcn_mfma_f32_16x16x32_f16(afr[rt][0], bl0, cl, 0, 0, 0);
            cl = __builtin_amdgcn_mfma_f32_16x16x32_f16(afr[rt][1], bl1, cl, 0, 0, 0);
            #pragma unroll
            for (int r = 0; r < 4; ++r) {
                const float s = fmaf(cl[r], INV_LO, ch[r]);
                // per-lane cols ascend over ct -> strict > keeps first index
                if (s > best[rt][r]) bidx[rt][r] = mycol;
                best[rt][r] = fmaxf(best[rt][r], s);
            }
        }
        bh0 = nh0; bh1 = nh1; bl0 = nl0; bl1 = nl1;
    }

    // Cross-lane argmax over the 16 cols held by l15=0..15 (same quad).
    // Tie -> smaller index (jnp.argmax first-index semantics).
    #pragma unroll
    for (int m = 1; m < 16; m <<= 1) {
        #pragma unroll
        for (int rt = 0; rt < 4; ++rt)
            #pragma unroll
            for (int r = 0; r < 4; ++r) {
                const float ov = __shfl_xor(best[rt][r], m, 64);
                const int   oi = __shfl_xor(bidx[rt][r], m, 64);
                if (ov > best[rt][r] ||
                    (ov == best[rt][r] && oi < bidx[rt][r])) {
                    best[rt][r] = ov; bidx[rt][r] = oi;
                }
            }
    }

    if (l15 == 0) {
        #pragma unroll
        for (int rt = 0; rt < 4; ++rt)
            #pragma unroll
            for (int r = 0; r < 4; ++r) {
                const int row = rowbase + rt * 16 + quad * 4 + r;
                pbest[(size_t)row * NCHUNK + chunk] = best[rt][r];
                pidx [(size_t)row * NCHUNK + chunk] = bidx[rt][r];
            }
    }
}

// ---------------------------------------------------------------------------
// Fold the 8 chunk partials (ascending chunk + strict > == global first-index
// argmax), gather LUT, write out (1024,8,10,2).
__global__ void reduce_lut_kernel(const float* __restrict__ pbest,
                                  const int*   __restrict__ pidx,
                                  const float* __restrict__ LUT,  // (10,4096,2)
                                  float* __restrict__ out) {
    const int row = blockIdx.x * blockDim.x + threadIdx.x;
    if (row >= M_ROWS) return;
    float best = -INFINITY;
    int   bi   = 0;
    #pragma unroll
    for (int ch = 0; ch < NCHUNK; ++ch) {
        const float bv = pbest[(size_t)row * NCHUNK + ch];
        const int   ix = pidx [(size_t)row * NCHUNK + ch];
        if (bv > best) { best = bv; bi = ix; }
    }
    const int pair = row / 10;
    const int c2   = row - pair * 10;
    const float* l = LUT + ((size_t)c2 * NCOLS + bi) * 2;
    out[row * 2 + 0] = l[0];
    out[row * 2 + 1] = l[1];
}

// ---------------------------------------------------------------------------
extern "C" void kernel_launch(void* const* d_in, const int* in_sizes, int n_in,
                              void* d_out, int out_size, void* d_ws, size_t ws_size,
                              hipStream_t stream) {
    const float* x   = (const float*)d_in[0];  // 1024*480
    const float* S   = (const float*)d_in[1];  // 30*2*15
    const float* T   = (const float*)d_in[2];  // 30*15
    const float* H   = (const float*)d_in[3];  // 45*4096
    const float* LUT = (const float*)d_in[4];  // 10*4096*2
    float* out = (float*)d_out;                // 1024*8*10*2

    _Float16* A   = (_Float16*)d_ws;                          // 81920*64
    _Float16* Bhi = A + (size_t)M_ROWS * KPAD;                // 4096*64
    _Float16* Blo = Bhi + (size_t)NCOLS * KPAD;               // 4096*64
    float*  pbest = (float*)(Blo + (size_t)NCOLS * KPAD);     // 81920*8
    int*    pidx  = (int*)(pbest + (size_t)M_ROWS * NCHUNK);  // 81920*8

    build_A_kernel<<<M_ROWS / 256, 256, 0, stream>>>(x, S, T, A);
    build_B_kernel<<<NCOLS / 256, 256, 0, stream>>>(H, Bhi, Blo);
    // 10240 waves = 1280 row-groups x 8 chunks; 4 waves/block, chunk-uniform blocks
    score_argmax_kernel<<<2560, 256, 0, stream>>>(A, Bhi, Blo, pbest, pidx);
    reduce_lut_kernel<<<M_ROWS / 256, 256, 0, stream>>>(pbest, pidx, LUT, out);
}

// Round 4
// 233.720 us; speedup vs baseline: 1.0807x; 1.0807x over previous
//
#include <hip/hip_runtime.h>
#include <math.h>

// Problem constants (N = 1024)
#define M_ROWS  81920            // 1024*8*10 score rows
#define NCOLS   4096
#define KPAD    64               // 45 padded to 64 (2 MFMA k-tiles)
#define NCHUNK  4
#define CHUNKC  (NCOLS / NCHUNK) // 1024 cols per chunk
#define CTILES  (CHUNKC / 16)    // 64 col-tiles per chunk (even)
#define LO_SCALE 4096.0f         // 2^12: keeps f16 residuals out of subnormal range
#define INV_LO   (1.0f / 4096.0f)

typedef _Float16 f16x8 __attribute__((ext_vector_type(8)));
typedef float    f32x4 __attribute__((ext_vector_type(4)));

// ws layout (~14.2 MB). ORDER MATTERS: the pipelined GEMM overreads up to
// 4 KB past the end of Bhi (lands in Blo) and past Blo (lands in pbest) on
// its final prefetch — values unused, but the memory must be valid.
//   A    : _Float16[81920 * 64]                         10.49 MB
//   Bhi  : _Float16[4096 * 64]   ([col][k], pad zeroed)  0.52 MB
//   Blo  : _Float16[4096 * 64]   (residual * 2^12)       0.52 MB
//   pbest: float[81920 * 4]                              1.31 MB
//   pidx : int  [81920 * 4]                              1.31 MB

// ---------------------------------------------------------------------------
// Fused A/B build. Blocks [0,320): A rows. Blocks [320,336): B columns.
__global__ void build_AB_kernel(const float* __restrict__ x,
                                const float* __restrict__ S,
                                const float* __restrict__ T,
                                const float* __restrict__ H,
                                _Float16* __restrict__ A,
                                _Float16* __restrict__ Bhi,
                                _Float16* __restrict__ Blo) {
    if (blockIdx.x < 320) {
        // ---- build A: y[row][k] = sign(x4·S - T - 1e-4), exactly ±1/0 in f16
        const int row = blockIdx.x * 256 + threadIdx.x;
        const int pair = row / 10;
        const int c2   = row - pair * 10;
        const int a    = pair >> 3;
        const int b    = pair & 7;
        const float* xp = x + a * 480 + b * 60;
        _Float16 y[KPAD];
        #pragma unroll
        for (int j = 0; j < 45; ++j) {
            const int c = c2 * 3 + j / 15;    // constant-folded by unroll
            const int k = j % 15;
            const float x0 = xp[c * 2 + 0];
            const float x1 = xp[c * 2 + 1];
            float v = x0 * S[(c * 2 + 0) * 15 + k] + x1 * S[(c * 2 + 1) * 15 + k];
            v = v - T[c * 15 + k] - 1e-4f;
            y[j] = (v > 0.f) ? (_Float16)1.f : ((v < 0.f) ? (_Float16)-1.f : (_Float16)0.f);
        }
        #pragma unroll
        for (int j = 45; j < KPAD; ++j) y[j] = (_Float16)0.f;
        f16x8* dst = (f16x8*)(A + (size_t)row * KPAD);   // 128 B/row, 16B-aligned
        const f16x8* src = (const f16x8*)y;
        #pragma unroll
        for (int q = 0; q < KPAD / 8; ++q) dst[q] = src[q];
    } else {
        // ---- build B: split H (45 x 4096) into hi/lo f16, [col][k] layout
        const int n = (blockIdx.x - 320) * 256 + threadIdx.x;
        _Float16 hi[KPAD], lo[KPAD];
        #pragma unroll
        for (int k = 0; k < 45; ++k) {
            const float h = H[k * NCOLS + n];
            const _Float16 h1 = (_Float16)h;
            hi[k] = h1;
            lo[k] = (_Float16)((h - (float)h1) * LO_SCALE);
        }
        #pragma unroll
        for (int k = 45; k < KPAD; ++k) { hi[k] = (_Float16)0.f; lo[k] = (_Float16)0.f; }
        f16x8* dh = (f16x8*)(Bhi + (size_t)n * KPAD);
        f16x8* dl = (f16x8*)(Blo + (size_t)n * KPAD);
        const f16x8* sh = (const f16x8*)hi;
        const f16x8* sl = (const f16x8*)lo;
        #pragma unroll
        for (int q = 0; q < KPAD / 8; ++q) { dh[q] = sh[q]; dl[q] = sl[q]; }
    }
}

// ---------------------------------------------------------------------------
// MFMA GEMM + fused argmax, branch-free 2x-unrolled software pipeline.
// wave = 64 rows (4 row-tiles) x 1024-col chunk; block's 4 waves share a chunk
// (L1 reuse on B). C layout (m89-verified): row = quad*4 + reg, col = lane&15.
__global__ __launch_bounds__(256) void score_argmax_kernel(
        const _Float16* __restrict__ A,
        const _Float16* __restrict__ Bhi,
        const _Float16* __restrict__ Blo,
        float* __restrict__ pbest,
        int*   __restrict__ pidx) {
    const int tid  = threadIdx.x;
    const int lane = tid & 63;
    const int l15  = lane & 15;
    const int quad = lane >> 4;
    const int w     = blockIdx.x * 4 + (tid >> 6);    // [0, 5120)
    const int chunk = w / 1280;                        // block-uniform (1280 % 4 == 0)
    const int rg    = w - chunk * 1280;
    const int rowbase = rg * 64;

    // A fragments: A[m=lane&15][k=quad*8+j], 2 k-tiles x 4 row-tiles.
    f16x8 afr[4][2];
    #pragma unroll
    for (int rt = 0; rt < 4; ++rt)
        #pragma unroll
        for (int kt = 0; kt < 2; ++kt)
            afr[rt][kt] = *(const f16x8*)(A + (size_t)(rowbase + rt * 16 + l15) * KPAD
                                            + kt * 32 + quad * 8);

    float best[4][4];
    int   bidx[4][4];
    #pragma unroll
    for (int rt = 0; rt < 4; ++rt)
        #pragma unroll
        for (int r = 0; r < 4; ++r) { best[rt][r] = -INFINITY; bidx[rt][r] = 0; }

    const int colbase0 = chunk * CHUNKC;
    const int mycol0   = colbase0 + l15;              // per-lane column anchor
    const _Float16* hbase = Bhi + (size_t)(colbase0 + l15) * KPAD + quad * 8;
    const _Float16* lbase = Blo + (size_t)(colbase0 + l15) * KPAD + quad * 8;
    const size_t TS = (size_t)16 * KPAD;              // halves per 16-col tile

    // two register sets (even/odd tiles); all loads unconditional.
    f16x8 eh0, eh1, el0, el1, oh0, oh1, ol0, ol1;
    eh0 = *(const f16x8*)(hbase);
    eh1 = *(const f16x8*)(hbase + 32);
    el0 = *(const f16x8*)(lbase);
    el1 = *(const f16x8*)(lbase + 32);

    for (int ct = 0; ct < CTILES; ct += 2) {
        // prefetch odd tile ct+1 (ct+1 <= CTILES-1, always in-chunk)
        {
            const _Float16* hp = hbase + (size_t)(ct + 1) * TS;
            const _Float16* lp = lbase + (size_t)(ct + 1) * TS;
            oh0 = *(const f16x8*)(hp);
            oh1 = *(const f16x8*)(hp + 32);
            ol0 = *(const f16x8*)(lp);
            ol1 = *(const f16x8*)(lp + 32);
        }
        // compute even tile ct
        #pragma unroll
        for (int rt = 0; rt < 4; ++rt) {
            f32x4 ch = {0.f, 0.f, 0.f, 0.f};
            f32x4 cl = {0.f, 0.f, 0.f, 0.f};
            ch = __builtin_amdgcn_mfma_f32_16x16x32_f16(afr[rt][0], eh0, ch, 0, 0, 0);
            ch = __builtin_amdgcn_mfma_f32_16x16x32_f16(afr[rt][1], eh1, ch, 0, 0, 0);
            cl = __builtin_amdgcn_mfma_f32_16x16x32_f16(afr[rt][0], el0, cl, 0, 0, 0);
            cl = __builtin_amdgcn_mfma_f32_16x16x32_f16(afr[rt][1], el1, cl, 0, 0, 0);
            const int mycol = mycol0 + ct * 16;
            #pragma unroll
            for (int r = 0; r < 4; ++r) {
                const float s = fmaf(cl[r], INV_LO, ch[r]);
                if (s > best[rt][r]) bidx[rt][r] = mycol;    // cols ascend: > keeps first
                best[rt][r] = fmaxf(best[rt][r], s);
            }
        }
        // prefetch even tile ct+2 (may overread <=4KB past chunk/arrays: valid ws)
        {
            const _Float16* hp = hbase + (size_t)(ct + 2) * TS;
            const _Float16* lp = lbase + (size_t)(ct + 2) * TS;
            eh0 = *(const f16x8*)(hp);
            eh1 = *(const f16x8*)(hp + 32);
            el0 = *(const f16x8*)(lp);
            el1 = *(const f16x8*)(lp + 32);
        }
        // compute odd tile ct+1
        #pragma unroll
        for (int rt = 0; rt < 4; ++rt) {
            f32x4 ch = {0.f, 0.f, 0.f, 0.f};
            f32x4 cl = {0.f, 0.f, 0.f, 0.f};
            ch = __builtin_amdgcn_mfma_f32_16x16x32_f16(afr[rt][0], oh0, ch, 0, 0, 0);
            ch = __builtin_amdgcn_mfma_f32_16x16x32_f16(afr[rt][1], oh1, ch, 0, 0, 0);
            cl = __builtin_amdgcn_mfma_f32_16x16x32_f16(afr[rt][0], ol0, cl, 0, 0, 0);
            cl = __builtin_amdgcn_mfma_f32_16x16x32_f16(afr[rt][1], ol1, cl, 0, 0, 0);
            const int mycol = mycol0 + (ct + 1) * 16;
            #pragma unroll
            for (int r = 0; r < 4; ++r) {
                const float s = fmaf(cl[r], INV_LO, ch[r]);
                if (s > best[rt][r]) bidx[rt][r] = mycol;
                best[rt][r] = fmaxf(best[rt][r], s);
            }
        }
    }

    // Cross-lane argmax over the 16 cols held by l15=0..15 (same quad).
    // Tie -> smaller index (jnp.argmax first-index semantics).
    #pragma unroll
    for (int m = 1; m < 16; m <<= 1) {
        #pragma unroll
        for (int rt = 0; rt < 4; ++rt)
            #pragma unroll
            for (int r = 0; r < 4; ++r) {
                const float ov = __shfl_xor(best[rt][r], m, 64);
                const int   oi = __shfl_xor(bidx[rt][r], m, 64);
                if (ov > best[rt][r] ||
                    (ov == best[rt][r] && oi < bidx[rt][r])) {
                    best[rt][r] = ov; bidx[rt][r] = oi;
                }
            }
    }

    if (l15 == 0) {
        #pragma unroll
        for (int rt = 0; rt < 4; ++rt)
            #pragma unroll
            for (int r = 0; r < 4; ++r) {
                const int row = rowbase + rt * 16 + quad * 4 + r;
                pbest[(size_t)row * NCHUNK + chunk] = best[rt][r];
                pidx [(size_t)row * NCHUNK + chunk] = bidx[rt][r];
            }
    }
}

// ---------------------------------------------------------------------------
// Fold the 4 chunk partials (ascending chunk + strict > == global first-index
// argmax), gather LUT, write out (1024,8,10,2).
__global__ void reduce_lut_kernel(const float* __restrict__ pbest,
                                  const int*   __restrict__ pidx,
                                  const float* __restrict__ LUT,  // (10,4096,2)
                                  float* __restrict__ out) {
    const int row = blockIdx.x * blockDim.x + threadIdx.x;
    if (row >= M_ROWS) return;
    float best = -INFINITY;
    int   bi   = 0;
    #pragma unroll
    for (int ch = 0; ch < NCHUNK; ++ch) {
        const float bv = pbest[(size_t)row * NCHUNK + ch];
        const int   ix = pidx [(size_t)row * NCHUNK + ch];
        if (bv > best) { best = bv; bi = ix; }
    }
    const int pair = row / 10;
    const int c2   = row - pair * 10;
    const float* l = LUT + ((size_t)c2 * NCOLS + bi) * 2;
    out[row * 2 + 0] = l[0];
    out[row * 2 + 1] = l[1];
}

// ---------------------------------------------------------------------------
extern "C" void kernel_launch(void* const* d_in, const int* in_sizes, int n_in,
                              void* d_out, int out_size, void* d_ws, size_t ws_size,
                              hipStream_t stream) {
    const float* x   = (const float*)d_in[0];  // 1024*480
    const float* S   = (const float*)d_in[1];  // 30*2*15
    const float* T   = (const float*)d_in[2];  // 30*15
    const float* H   = (const float*)d_in[3];  // 45*4096
    const float* LUT = (const float*)d_in[4];  // 10*4096*2
    float* out = (float*)d_out;                // 1024*8*10*2

    _Float16* A   = (_Float16*)d_ws;                          // 81920*64
    _Float16* Bhi = A + (size_t)M_ROWS * KPAD;                // 4096*64
    _Float16* Blo = Bhi + (size_t)NCOLS * KPAD;               // 4096*64
    float*  pbest = (float*)(Blo + (size_t)NCOLS * KPAD);     // 81920*4
    int*    pidx  = (int*)(pbest + (size_t)M_ROWS * NCHUNK);  // 81920*4

    build_AB_kernel<<<336, 256, 0, stream>>>(x, S, T, H, A, Bhi, Blo);
    // 5120 waves = 1280 row-groups x 4 chunks; 4 waves/block, chunk-uniform blocks
    score_argmax_kernel<<<1280, 256, 0, stream>>>(A, Bhi, Blo, pbest, pidx);
    reduce_lut_kernel<<<M_ROWS / 256, 256, 0, stream>>>(pbest, pidx, LUT, out);
}

// Round 5
// 190.098 us; speedup vs baseline: 1.3287x; 1.2295x over previous
//
#include <hip/hip_runtime.h>
#include <math.h>

// Problem constants (N = 1024)
#define M_ROWS  81920            // 1024*8*10 score rows
#define NCOLS   4096
#define KPAD    48               // 45 padded to 48 (3 k-tiles of 16 for 32x32x16)
#define NCHUNK  4
#define CHUNKC  (NCOLS / NCHUNK) // 1024 cols per chunk
#define CROUNDS (CHUNKC / 32)    // 32 col-rounds of 32 cols
#define LO_SCALE 4096.0f         // 2^12: keeps f16 residuals out of subnormal range
#define INV_LO   (1.0f / 4096.0f)

typedef _Float16 f16x8  __attribute__((ext_vector_type(8)));
typedef float    f32x16 __attribute__((ext_vector_type(16)));

// ws layout (~3.4 MB). ORDER MATTERS: the pipelined GEMM overreads up to one
// 32-col round (~3 KB) past Bhi (lands in Blo) and past Blo (lands in pbest)
// on its final prefetch — values unused, memory must be valid.
//   Bhi  : _Float16[4096 * 48]   ([col][k], pad zeroed)   0.39 MB
//   Blo  : _Float16[4096 * 48]   (residual * 2^12)        0.39 MB
//   pbest: float[81920 * 4]                               1.31 MB
//   pidx : int  [81920 * 4]                               1.31 MB

// ---------------------------------------------------------------------------
// Build B: split H (45 x 4096, [d][n]) into hi/lo f16 in [col][k] layout,
// 48 k's per col (96 B stride, 16B-aligned), pad k=45..47 zeroed.
__global__ void build_B_kernel(const float* __restrict__ H,
                               _Float16* __restrict__ Bhi,
                               _Float16* __restrict__ Blo) {
    const int n = blockIdx.x * 256 + threadIdx.x;
    _Float16 hi[KPAD], lo[KPAD];
    #pragma unroll
    for (int k = 0; k < 45; ++k) {
        const float h = H[k * NCOLS + n];
        const _Float16 h1 = (_Float16)h;
        hi[k] = h1;
        lo[k] = (_Float16)((h - (float)h1) * LO_SCALE);
    }
    #pragma unroll
    for (int k = 45; k < KPAD; ++k) { hi[k] = (_Float16)0.f; lo[k] = (_Float16)0.f; }
    f16x8* dh = (f16x8*)(Bhi + (size_t)n * KPAD);
    f16x8* dl = (f16x8*)(Blo + (size_t)n * KPAD);
    const f16x8* sh = (const f16x8*)hi;
    const f16x8* sl = (const f16x8*)lo;
    #pragma unroll
    for (int q = 0; q < KPAD / 8; ++q) { dh[q] = sh[q]; dl[q] = sl[q]; }
}

// ---------------------------------------------------------------------------
// MFMA GEMM + fused argmax, 32x32x16 shape, inline A computation.
// wave = 64 rows (2 row-tiles of 32) x 1024-col chunk, 32-col rounds,
// branch-free double-buffered B prefetch. Block's 4 waves share a chunk.
// 32x32 layouts: A[m=lane&31][k=(lane>>5)*8+j]; B[k=(lane>>5)*8+j][n=lane&31];
// C/D: col=lane&31, row=(reg&3)+8*(reg>>2)+4*(lane>>5)   (m74/m101-verified).
__global__ __launch_bounds__(256, 2) void score_argmax_kernel(
        const float* __restrict__ x,   // (1024, 480)
        const float* __restrict__ S,   // (30, 2, 15)
        const float* __restrict__ T,   // (30, 15)
        const _Float16* __restrict__ Bhi,
        const _Float16* __restrict__ Blo,
        float* __restrict__ pbest,
        int*   __restrict__ pidx) {
    const int tid  = threadIdx.x;
    const int lane = tid & 63;
    const int l31  = lane & 31;
    const int half = lane >> 5;                       // 0 or 1
    const int chunk = blockIdx.x / 320;               // block-uniform
    const int rg    = (blockIdx.x - chunk * 320) * 4 + (tid >> 6);  // [0,1280)
    const int rowbase = rg * 64;

    // ---- inline A: afr[rt][kt][j] = y(rowbase + rt*32 + l31, kt*16 + half*8 + j)
    // y = sign(x4·S - T - 1e-4), exactly ±1/0 in f16; zero for k >= 45.
    f16x8 afr[2][3];
    #pragma unroll
    for (int rt = 0; rt < 2; ++rt) {
        const int row  = rowbase + rt * 32 + l31;
        const int pair = row / 10;
        const int c2   = row - pair * 10;
        const int a    = pair >> 3;
        const int b    = pair & 7;
        const float* xp = x + a * 480 + b * 60;
        #pragma unroll
        for (int kt = 0; kt < 3; ++kt) {
            #pragma unroll
            for (int j = 0; j < 8; ++j) {
                const int k    = kt * 16 + half * 8 + j;     // [0,48)
                const bool pad = (k >= 45);
                const int kcl  = pad ? 0 : k;                // clamp for safe addrs
                const int cc   = kcl / 15;                   // const-divisor magic
                const int kk   = kcl - cc * 15;
                const int c    = c2 * 3 + cc;
                const float x0 = xp[c * 2 + 0];
                const float x1 = xp[c * 2 + 1];
                float v = x0 * S[(c * 2 + 0) * 15 + kk] + x1 * S[(c * 2 + 1) * 15 + kk];
                v = v - T[c * 15 + kk] - 1e-4f;
                const float yv = (v > 0.f) ? 1.f : ((v < 0.f) ? -1.f : 0.f);
                afr[rt][kt][j] = pad ? (_Float16)0.f : (_Float16)yv;
            }
        }
    }

    float best[2][16];
    int   bidx[2][16];
    #pragma unroll
    for (int rt = 0; rt < 2; ++rt)
        #pragma unroll
        for (int e = 0; e < 16; ++e) { best[rt][e] = -INFINITY; bidx[rt][e] = 0; }

    const int colbase0 = chunk * CHUNKC;
    // per-lane B base: col = colbase0 + l31, byte = col*96 + half*16 (+kt*32)
    const _Float16* hbase = Bhi + (size_t)(colbase0 + l31) * KPAD + half * 8;
    const _Float16* lbase = Blo + (size_t)(colbase0 + l31) * KPAD + half * 8;
    const size_t RS = (size_t)32 * KPAD;              // halves per 32-col round

    // double-buffered B fragments (hi/lo x 3 k-tiles); all loads unconditional.
    f16x8 cb[6], nb[6];
    #pragma unroll
    for (int kt = 0; kt < 3; ++kt) {
        cb[kt]     = *(const f16x8*)(hbase + kt * 16);
        cb[3 + kt] = *(const f16x8*)(lbase + kt * 16);
    }

    for (int ct = 0; ct < CROUNDS; ++ct) {
        // prefetch round ct+1 (final iter overreads <=3KB into adjacent ws: valid)
        {
            const _Float16* hp = hbase + (size_t)(ct + 1) * RS;
            const _Float16* lp = lbase + (size_t)(ct + 1) * RS;
            #pragma unroll
            for (int kt = 0; kt < 3; ++kt) {
                nb[kt]     = *(const f16x8*)(hp + kt * 16);
                nb[3 + kt] = *(const f16x8*)(lp + kt * 16);
            }
        }
        const int mycol = colbase0 + ct * 32 + l31;   // same col for all 32 scores
        #pragma unroll
        for (int rt = 0; rt < 2; ++rt) {
            f32x16 ch = {0.f}; f32x16 cl = {0.f};
            #pragma unroll
            for (int e = 1; e < 16; ++e) { ch[e] = 0.f; cl[e] = 0.f; }
            ch = __builtin_amdgcn_mfma_f32_32x32x16_f16(afr[rt][0], cb[0], ch, 0, 0, 0);
            ch = __builtin_amdgcn_mfma_f32_32x32x16_f16(afr[rt][1], cb[1], ch, 0, 0, 0);
            ch = __builtin_amdgcn_mfma_f32_32x32x16_f16(afr[rt][2], cb[2], ch, 0, 0, 0);
            cl = __builtin_amdgcn_mfma_f32_32x32x16_f16(afr[rt][0], cb[3], cl, 0, 0, 0);
            cl = __builtin_amdgcn_mfma_f32_32x32x16_f16(afr[rt][1], cb[4], cl, 0, 0, 0);
            cl = __builtin_amdgcn_mfma_f32_32x32x16_f16(afr[rt][2], cb[5], cl, 0, 0, 0);
            #pragma unroll
            for (int e = 0; e < 16; ++e) {
                const float s = fmaf(cl[e], INV_LO, ch[e]);
                if (s > best[rt][e]) bidx[rt][e] = mycol;   // cols ascend: > keeps first
                best[rt][e] = fmaxf(best[rt][e], s);
            }
        }
        #pragma unroll
        for (int q = 0; q < 6; ++q) cb[q] = nb[q];
    }

    // Cross-lane argmax over the 32 cols held by l31=0..31 (same half).
    // Tie -> smaller index (jnp.argmax first-index semantics).
    #pragma unroll
    for (int m = 1; m < 32; m <<= 1) {
        #pragma unroll
        for (int rt = 0; rt < 2; ++rt)
            #pragma unroll
            for (int e = 0; e < 16; ++e) {
                const float ov = __shfl_xor(best[rt][e], m, 64);
                const int   oi = __shfl_xor(bidx[rt][e], m, 64);
                if (ov > best[rt][e] ||
                    (ov == best[rt][e] && oi < bidx[rt][e])) {
                    best[rt][e] = ov; bidx[rt][e] = oi;
                }
            }
    }

    if (l31 == 0) {   // lanes 0 and 32 write their half's rows
        #pragma unroll
        for (int rt = 0; rt < 2; ++rt)
            #pragma unroll
            for (int e = 0; e < 16; ++e) {
                const int row = rowbase + rt * 32 + (e & 3) + 8 * (e >> 2) + 4 * half;
                pbest[(size_t)row * NCHUNK + chunk] = best[rt][e];
                pidx [(size_t)row * NCHUNK + chunk] = bidx[rt][e];
            }
    }
}

// ---------------------------------------------------------------------------
// Fold the 4 chunk partials (ascending chunk + strict > == global first-index
// argmax), gather LUT, write out (1024,8,10,2).
__global__ void reduce_lut_kernel(const float* __restrict__ pbest,
                                  const int*   __restrict__ pidx,
                                  const float* __restrict__ LUT,  // (10,4096,2)
                                  float* __restrict__ out) {
    const int row = blockIdx.x * blockDim.x + threadIdx.x;
    if (row >= M_ROWS) return;
    float best = -INFINITY;
    int   bi   = 0;
    #pragma unroll
    for (int ch = 0; ch < NCHUNK; ++ch) {
        const float bv = pbest[(size_t)row * NCHUNK + ch];
        const int   ix = pidx [(size_t)row * NCHUNK + ch];
        if (bv > best) { best = bv; bi = ix; }
    }
    const int pair = row / 10;
    const int c2   = row - pair * 10;
    const float* l = LUT + ((size_t)c2 * NCOLS + bi) * 2;
    out[row * 2 + 0] = l[0];
    out[row * 2 + 1] = l[1];
}

// ---------------------------------------------------------------------------
extern "C" void kernel_launch(void* const* d_in, const int* in_sizes, int n_in,
                              void* d_out, int out_size, void* d_ws, size_t ws_size,
                              hipStream_t stream) {
    const float* x   = (const float*)d_in[0];  // 1024*480
    const float* S   = (const float*)d_in[1];  // 30*2*15
    const float* T   = (const float*)d_in[2];  // 30*15
    const float* H   = (const float*)d_in[3];  // 45*4096
    const float* LUT = (const float*)d_in[4];  // 10*4096*2
    float* out = (float*)d_out;                // 1024*8*10*2

    _Float16* Bhi = (_Float16*)d_ws;                          // 4096*48
    _Float16* Blo = Bhi + (size_t)NCOLS * KPAD;               // 4096*48
    float*  pbest = (float*)(Blo + (size_t)NCOLS * KPAD);     // 81920*4
    int*    pidx  = (int*)(pbest + (size_t)M_ROWS * NCHUNK);  // 81920*4

    build_B_kernel<<<16, 256, 0, stream>>>(H, Bhi, Blo);
    // 5120 waves = 1280 row-groups x 4 chunks; 4 waves/block, chunk-uniform blocks
    score_argmax_kernel<<<1280, 256, 0, stream>>>(x, S, T, Bhi, Blo, pbest, pidx);
    reduce_lut_kernel<<<M_ROWS / 256, 256, 0, stream>>>(pbest, pidx, LUT, out);
}